// Round 1
// 959.263 us; speedup vs baseline: 2.4096x; 2.4096x over previous
//
#include <hip/hip_runtime.h>

#define BB 8
#define SS 128
#define NN 64
#define DKK 256
#define HH 8
#define DHH 32
#define OUT0_ELEMS 16777216   // B*S*N*DK
// weights elems: B*H*S*N*N = 33554432

typedef unsigned short u16;
typedef __attribute__((ext_vector_type(8))) short short8;   // 8 bf16 (4 VGPRs)
typedef __attribute__((ext_vector_type(4))) float f32x4;    // MFMA C/D frag

__device__ __forceinline__ float bf2f(u16 u) {
    union { unsigned int ui; float f; } c;
    c.ui = ((unsigned int)u) << 16;
    return c.f;
}
__device__ __forceinline__ u16 f2bf(float f) {
    union { float f; unsigned int u; } c;
    c.f = f;
    unsigned int u = c.u;
    return (u16)((u + 0x7fffu + ((u >> 16) & 1u)) >> 16);
}

// Skewed row offset for 36-float rows (+4 floats every 16 rows): breaks the
// 576-dword (bank-identical) aliasing between qq row-groups in scores/PV.
__device__ __forceinline__ int ro(int m) { return m * 36 + ((m >> 4) << 2); }

// Detect input dtype (see previous session notes): flag=1 => f32 mode.
__global__ void k_detect(const u16* __restrict__ w, int* __restrict__ flag) {
    __shared__ int cnt;
    if (threadIdx.x == 0) cnt = 0;
    __syncthreads();
    int bad = 0;
    for (int i = threadIdx.x; i < 8192; i += 256) {
        float v = bf2f(w[i]);
        if (!(fabsf(v) <= 1e3f)) bad++;
    }
    if (bad) atomicAdd(&cnt, bad);
    __syncthreads();
    if (threadIdx.x == 0) flag[0] = (cnt > 64) ? 1 : 0;
}

// ---------------------------------------------------------------------------
// k_wt: transpose the 4 weight matrices into workspace as bf16 WT[n][k]
// (hi part always; lo = bf16(x - hi) residual only in f32 mode).
// ws layout: [0,4) flag; [512, 512+512K) hi WQ,WK,WV,WO; then 512K of lo.
// ---------------------------------------------------------------------------
__global__ void k_wt(const void* __restrict__ w0, const void* __restrict__ w1,
                     const void* __restrict__ w2, const void* __restrict__ w3,
                     void* __restrict__ ws, const int* __restrict__ flag) {
    const int f32m = flag[0];
    const int p = blockIdx.x >> 6;
    const int chunk = blockIdx.x & 63;
    const void* W = (p == 0) ? w0 : (p == 1) ? w1 : (p == 2) ? w2 : w3;
    u16* hi = (u16*)((char*)ws + 512) + (size_t)p * 65536;
    u16* lo = hi + 4 * 65536;
#pragma unroll
    for (int ii = 0; ii < 4; ++ii) {
        int o = chunk * 1024 + ii * 256 + threadIdx.x;   // o = n*256 + k
        int n = o >> 8, k = o & 255;
        if (f32m) {
            float x = ((const float*)W)[k * 256 + n];
            u16 h = f2bf(x);
            hi[o] = h;
            lo[o] = f2bf(x - bf2f(h));
        } else {
            hi[o] = ((const u16*)W)[k * 256 + n];
        }
    }
}

// ---------------------------------------------------------------------------
// MFMA attention: one block per (b,s,h), 4 waves; wave w owns agent rows
// [16w,16w+16). Projections via mfma_f32_16x16x32_bf16 (f32 mode: hi/lo
// split, 3 MFMAs per tile -> ~f32 precision). A-frags straight from global;
// B-frags from the pre-transposed WT in ws. Q/K/V -> LDS (skewed layout),
// then the proven VALU scores/softmax/PV epilogue (unchanged numerics).
// ---------------------------------------------------------------------------
template <bool F32>
__global__ __launch_bounds__(256) void k_attn_mfma(
    const void* __restrict__ qv, const void* __restrict__ kv, const void* __restrict__ vv,
    const void* __restrict__ bQv, const void* __restrict__ bKv, const void* __restrict__ bVv,
    const void* __restrict__ ws, void* __restrict__ outv, const int* __restrict__ flag)
{
    if ((flag[0] != 0) != F32) return;

    __shared__ float sQ[2320], sK[2320], sV[2320];

    const int t = threadIdx.x;
    const int wv_ = t >> 6;          // wave id = M-tile
    const int lane = t & 63;
    const int li = lane & 15;        // A row-in-tile / B,C col-in-tile
    const int lg = lane >> 4;        // K-subgroup / C row-group
    const int bs = blockIdx.x >> 3;
    const int h = blockIdx.x & 7;
    const int b = bs >> 7;
    const int s = bs & 127;

    const u16* wt = (const u16*)((const char*)ws + 512);

    for (int p = 0; p < 3; ++p) {
        const void* Xp = (p == 0) ? qv : (p == 1) ? kv : vv;
        const void* bp = (p == 0) ? bQv : (p == 1) ? bKv : bVv;
        float bias0, bias1;
        if constexpr (F32) {
            bias0 = ((const float*)bp)[h * 32 + li];
            bias1 = ((const float*)bp)[h * 32 + 16 + li];
        } else {
            bias0 = bf2f(((const u16*)bp)[h * 32 + li]);
            bias1 = bf2f(((const u16*)bp)[h * 32 + 16 + li]);
        }
        f32x4 c0 = {bias0, bias0, bias0, bias0};
        f32x4 c1 = {bias1, bias1, bias1, bias1};
        const u16* wtp = wt + (size_t)p * 65536;
        const u16* wtl = wtp + 4 * 65536;
        const size_t arow = ((size_t)bs * 64 + wv_ * 16 + li) * 256;
#pragma unroll
        for (int ks = 0; ks < 8; ++ks) {
            const int kof = ks * 32 + lg * 8;
            short8 ah, al;
            if constexpr (F32) {
                const float* xp = (const float*)Xp + arow + kof;
                float4 x0 = *(const float4*)xp;
                float4 x1 = *(const float4*)(xp + 4);
                float x8[8] = {x0.x, x0.y, x0.z, x0.w, x1.x, x1.y, x1.z, x1.w};
#pragma unroll
                for (int j = 0; j < 8; ++j) {
                    u16 hh = f2bf(x8[j]);
                    ah[j] = (short)hh;
                    al[j] = (short)f2bf(x8[j] - bf2f(hh));
                }
            } else {
                ah = *(const short8*)((const u16*)Xp + arow + kof);
            }
            const u16* bp0 = wtp + (size_t)(h * 32 + li) * 256 + kof;
            const u16* bp1 = wtp + (size_t)(h * 32 + 16 + li) * 256 + kof;
            short8 b0 = *(const short8*)bp0;
            short8 b1 = *(const short8*)bp1;
            c0 = __builtin_amdgcn_mfma_f32_16x16x32_bf16(ah, b0, c0, 0, 0, 0);
            c1 = __builtin_amdgcn_mfma_f32_16x16x32_bf16(ah, b1, c1, 0, 0, 0);
            if constexpr (F32) {
                short8 l0 = *(const short8*)(wtl + (size_t)(h * 32 + li) * 256 + kof);
                short8 l1 = *(const short8*)(wtl + (size_t)(h * 32 + 16 + li) * 256 + kof);
                c0 = __builtin_amdgcn_mfma_f32_16x16x32_bf16(ah, l0, c0, 0, 0, 0);
                c0 = __builtin_amdgcn_mfma_f32_16x16x32_bf16(al, b0, c0, 0, 0, 0);
                c1 = __builtin_amdgcn_mfma_f32_16x16x32_bf16(ah, l1, c1, 0, 0, 0);
                c1 = __builtin_amdgcn_mfma_f32_16x16x32_bf16(al, b1, c1, 0, 0, 0);
            }
        }
        float* dst = (p == 0) ? sQ : (p == 1) ? sK : sV;
        const int row0 = wv_ * 16 + lg * 4;
#pragma unroll
        for (int r = 0; r < 4; ++r) {
            int o = ro(row0 + r);
            dst[o + li] = c0[r];
            dst[o + 16 + li] = c1[r];
        }
    }
    __syncthreads();

    // ---- scores + softmax; thread (n,qq) owns m = qq*16 .. qq*16+15 ----
    const int n = t >> 2;
    const int qq = t & 3;
    float qr[32];
#pragma unroll
    for (int j = 0; j < 8; ++j) {
        float4 f = *(const float4*)&sQ[ro(n) + j * 4];
        qr[j * 4 + 0] = f.x; qr[j * 4 + 1] = f.y;
        qr[j * 4 + 2] = f.z; qr[j * 4 + 3] = f.w;
    }
    const float scale = 0.17677669529663687f;  // 1/sqrt(32)
    float sc[16];
#pragma unroll
    for (int i = 0; i < 16; ++i) {
        int m = qq * 16 + i;
        float d = 0.f;
        const float* kr = &sK[ro(m)];
#pragma unroll
        for (int j = 0; j < 8; ++j) {
            float4 f = *(const float4*)(kr + j * 4);
            d += qr[j * 4 + 0] * f.x + qr[j * 4 + 1] * f.y +
                 qr[j * 4 + 2] * f.z + qr[j * 4 + 3] * f.w;
        }
        sc[i] = d * scale;
    }
    float mx = sc[0];
#pragma unroll
    for (int i = 1; i < 16; ++i) mx = fmaxf(mx, sc[i]);
    mx = fmaxf(mx, __shfl_xor(mx, 1));
    mx = fmaxf(mx, __shfl_xor(mx, 2));
    float sum = 0.f;
#pragma unroll
    for (int i = 0; i < 16; ++i) { sc[i] = __expf(sc[i] - mx); sum += sc[i]; }
    sum += __shfl_xor(sum, 1);
    sum += __shfl_xor(sum, 2);
    const float inv = 1.0f / sum;
#pragma unroll
    for (int i = 0; i < 16; ++i) sc[i] *= inv;

    // weights out
    {
        size_t wbase = ((((size_t)b * HH + h) * SS + s) * NN + n) * NN + (size_t)qq * 16;
        if constexpr (F32) {
            float* wf = (float*)outv + (size_t)OUT0_ELEMS + wbase;
#pragma unroll
            for (int g = 0; g < 4; ++g) {
                float4 f; f.x = sc[g*4]; f.y = sc[g*4+1]; f.z = sc[g*4+2]; f.w = sc[g*4+3];
                *(float4*)(wf + g * 4) = f;
            }
        } else {
            u16* wo = (u16*)outv + (size_t)OUT0_ELEMS + wbase;
            union { u16 u[16]; uint4 v[2]; } wb;
#pragma unroll
            for (int i = 0; i < 16; ++i) wb.u[i] = f2bf(sc[i]);
            *(uint4*)wo = wb.v[0];
            *(uint4*)(wo + 8) = wb.v[1];
        }
    }

    // ---- P @ V ----
    float ao[32];
#pragma unroll
    for (int d = 0; d < 32; ++d) ao[d] = 0.f;
#pragma unroll
    for (int i = 0; i < 16; ++i) {
        int m = qq * 16 + i;
        float w = sc[i];
        const float* vr = &sV[ro(m)];
#pragma unroll
        for (int j = 0; j < 8; ++j) {
            float4 f = *(const float4*)(vr + j * 4);
            ao[j * 4 + 0] += w * f.x; ao[j * 4 + 1] += w * f.y;
            ao[j * 4 + 2] += w * f.z; ao[j * 4 + 3] += w * f.w;
        }
    }
#pragma unroll
    for (int d = 0; d < 32; ++d) {
        ao[d] += __shfl_xor(ao[d], 1);
        ao[d] += __shfl_xor(ao[d], 2);
    }
    {
        size_t abase = ((size_t)bs * NN + n) * DKK + h * DHH + (size_t)qq * 8;
        if constexpr (F32) {
            float* af = (float*)outv + abase;
            float4 f0, f1;
            f0.x = ao[qq*8+0]; f0.y = ao[qq*8+1]; f0.z = ao[qq*8+2]; f0.w = ao[qq*8+3];
            f1.x = ao[qq*8+4]; f1.y = ao[qq*8+5]; f1.z = ao[qq*8+6]; f1.w = ao[qq*8+7];
            *(float4*)af = f0;
            *(float4*)(af + 4) = f1;
        } else {
            union { u16 u[8]; uint4 v; } ob;
#pragma unroll
            for (int u = 0; u < 8; ++u) ob.u[u] = f2bf(ao[qq * 8 + u]);
            *(uint4*)((u16*)outv + abase) = ob.v;
        }
    }
}

// ---------------------------------------------------------------------------
// MFMA out-projection: one block per (b,s), 4 waves; wave w owns output rows
// [16w,16w+16). attn rows are pre-loaded into registers (bf16, matching the
// old path's rounding), so the in-place write is hazard-free. B-frags from
// WOt (hi [+lo in f32 mode]) in ws.
// ---------------------------------------------------------------------------
template <bool F32>
__global__ __launch_bounds__(256) void k_outproj_mfma(
    const void* __restrict__ ws, const void* __restrict__ bOv,
    void* __restrict__ outv, const int* __restrict__ flag)
{
    if ((flag[0] != 0) != F32) return;

    const int t = threadIdx.x;
    const int wv_ = t >> 6, lane = t & 63, li = lane & 15, lg = lane >> 4;
    const size_t base = (size_t)blockIdx.x * (NN * DKK);
    const u16* wt = (const u16*)((const char*)ws + 512) + (size_t)3 * 65536;
    const u16* wtl = wt + 4 * 65536;

    short8 a[8];
    const size_t arow = base + (size_t)(wv_ * 16 + li) * 256;
#pragma unroll
    for (int ks = 0; ks < 8; ++ks) {
        const int kof = ks * 32 + lg * 8;
        if constexpr (F32) {
            const float* xp = (const float*)outv + arow + kof;
            float4 x0 = *(const float4*)xp;
            float4 x1 = *(const float4*)(xp + 4);
            float x8[8] = {x0.x, x0.y, x0.z, x0.w, x1.x, x1.y, x1.z, x1.w};
#pragma unroll
            for (int j = 0; j < 8; ++j) a[ks][j] = (short)f2bf(x8[j]);
        } else {
            a[ks] = *(const short8*)((const u16*)outv + arow + kof);
        }
    }

    for (int nt = 0; nt < 16; ++nt) {
        const int col = nt * 16 + li;
        float bv;
        if constexpr (F32) bv = ((const float*)bOv)[col];
        else               bv = bf2f(((const u16*)bOv)[col]);
        f32x4 c = {bv, bv, bv, bv};
#pragma unroll
        for (int ks = 0; ks < 8; ++ks) {
            const int kof = ks * 32 + lg * 8;
            short8 bh = *(const short8*)(wt + (size_t)col * 256 + kof);
            c = __builtin_amdgcn_mfma_f32_16x16x32_bf16(a[ks], bh, c, 0, 0, 0);
            if constexpr (F32) {
                short8 bl = *(const short8*)(wtl + (size_t)col * 256 + kof);
                c = __builtin_amdgcn_mfma_f32_16x16x32_bf16(a[ks], bl, c, 0, 0, 0);
            }
        }
#pragma unroll
        for (int r = 0; r < 4; ++r) {
            size_t off = base + (size_t)(wv_ * 16 + lg * 4 + r) * 256 + col;
            if constexpr (F32) ((float*)outv)[off] = c[r];
            else               ((u16*)outv)[off] = f2bf(c[r]);
        }
    }
}

// ===========================================================================
// Fallback path (previous session's kernels, verbatim) — used if workspace
// is too small to hold the transposed weights.
// ===========================================================================
template <bool F32>
__global__ __launch_bounds__(256) void k_attn(
    const void* __restrict__ qv, const void* __restrict__ kv, const void* __restrict__ vv,
    const void* __restrict__ WQv, const void* __restrict__ bQv,
    const void* __restrict__ WKv, const void* __restrict__ bKv,
    const void* __restrict__ WVv, const void* __restrict__ bVv,
    void* __restrict__ outv, const int* __restrict__ flag)
{
    if ((flag[0] != 0) != F32) return;

    __shared__ __align__(16) char smem[60416];
    float (*sQ)[36] = (float (*)[36])(smem + 33792);
    float (*sK)[36] = (float (*)[36])(smem + 33792 + 9216);
    float (*sV)[32] = (float (*)[32])(smem + 33792 + 18432);

    const int t  = threadIdx.x;
    const int bs = blockIdx.x >> 3;
    const int h  = blockIdx.x & 7;
    const int b  = bs >> 7;
    const int s  = bs & 127;
    const int n  = t >> 2;
    const int qq = t & 3;
    const int colbase = h * DHH + qq * 8;
    const size_t xoff = (size_t)bs * (NN * DKK);

    for (int p = 0; p < 3; ++p) {
        const void* Xp = (p == 0) ? qv : (p == 1) ? kv : vv;
        const void* Wp_ = (p == 0) ? WQv : (p == 1) ? WKv : WVv;
        const void* bp_ = (p == 0) ? bQv : (p == 1) ? bKv : bVv;
        float acc[8];

        if constexpr (F32) {
            const float* bb = (const float*)bp_;
#pragma unroll
            for (int u = 0; u < 8; ++u) acc[u] = bb[colbase + u];
            const float* X = (const float*)Xp + xoff;
            const float* W = (const float*)Wp_ + colbase;
            float (*xsf)[132] = (float (*)[132])smem;
            for (int half = 0; half < 2; ++half) {
                __syncthreads();
#pragma unroll
                for (int i = 0; i < 8; ++i) {
                    int idx = t + (i << 8);
                    int r = idx >> 5;
                    int c4 = (idx & 31) << 2;
                    *(float4*)&xsf[r][c4] =
                        *(const float4*)(X + (size_t)r * DKK + (half << 7) + c4);
                }
                __syncthreads();
#pragma unroll 4
                for (int kk2 = 0; kk2 < 128; ++kk2) {
                    int kk = (half << 7) + kk2;
                    float x = xsf[n][kk2];
                    float4 w0 = *(const float4*)(W + (size_t)kk * DKK);
                    float4 w1 = *(const float4*)(W + (size_t)kk * DKK + 4);
                    acc[0] += x * w0.x; acc[1] += x * w0.y;
                    acc[2] += x * w0.z; acc[3] += x * w0.w;
                    acc[4] += x * w1.x; acc[5] += x * w1.y;
                    acc[6] += x * w1.z; acc[7] += x * w1.w;
                }
            }
        } else {
            const u16* bb = (const u16*)bp_;
#pragma unroll
            for (int u = 0; u < 8; ++u) acc[u] = bf2f(bb[colbase + u]);
            const u16* X = (const u16*)Xp + xoff;
            const u16* W = (const u16*)Wp_ + colbase;
            u16 (*xs)[264] = (u16 (*)[264])smem;
            __syncthreads();
#pragma unroll
            for (int i = 0; i < 8; ++i) {
                int idx = t + (i << 8);
                int r = idx >> 5;
                int c = (idx & 31) << 3;
                *(uint4*)&xs[r][c] = ((const uint4*)X)[idx];
            }
            __syncthreads();
#pragma unroll 4
            for (int kk = 0; kk < DKK; ++kk) {
                float x = bf2f(xs[n][kk]);
                uint4 wv = *(const uint4*)(W + (size_t)kk * DKK);
                const u16* w8 = (const u16*)&wv;
                acc[0] += x * bf2f(w8[0]); acc[1] += x * bf2f(w8[1]);
                acc[2] += x * bf2f(w8[2]); acc[3] += x * bf2f(w8[3]);
                acc[4] += x * bf2f(w8[4]); acc[5] += x * bf2f(w8[5]);
                acc[6] += x * bf2f(w8[6]); acc[7] += x * bf2f(w8[7]);
            }
        }

        if (p == 0) {
#pragma unroll
            for (int u = 0; u < 8; ++u) sQ[n][qq * 8 + u] = acc[u];
        } else if (p == 1) {
#pragma unroll
            for (int u = 0; u < 8; ++u) sK[n][qq * 8 + u] = acc[u];
        } else {
#pragma unroll
            for (int u = 0; u < 8; ++u) sV[n][qq * 8 + u] = acc[u];
        }
    }
    __syncthreads();

    float qr[32];
#pragma unroll
    for (int j = 0; j < 8; ++j) {
        float4 f = *(const float4*)&sQ[n][j * 4];
        qr[j * 4 + 0] = f.x; qr[j * 4 + 1] = f.y;
        qr[j * 4 + 2] = f.z; qr[j * 4 + 3] = f.w;
    }
    const float scale = 0.17677669529663687f;
    float sc[16];
#pragma unroll
    for (int i = 0; i < 16; ++i) {
        int m = qq * 16 + i;
        float d = 0.f;
#pragma unroll
        for (int j = 0; j < 8; ++j) {
            float4 f = *(const float4*)&sK[m][j * 4];
            d += qr[j * 4 + 0] * f.x + qr[j * 4 + 1] * f.y +
                 qr[j * 4 + 2] * f.z + qr[j * 4 + 3] * f.w;
        }
        sc[i] = d * scale;
    }
    float mx = sc[0];
#pragma unroll
    for (int i = 1; i < 16; ++i) mx = fmaxf(mx, sc[i]);
    mx = fmaxf(mx, __shfl_xor(mx, 1));
    mx = fmaxf(mx, __shfl_xor(mx, 2));
    float sum = 0.f;
#pragma unroll
    for (int i = 0; i < 16; ++i) { sc[i] = __expf(sc[i] - mx); sum += sc[i]; }
    sum += __shfl_xor(sum, 1);
    sum += __shfl_xor(sum, 2);
    const float inv = 1.0f / sum;
#pragma unroll
    for (int i = 0; i < 16; ++i) sc[i] *= inv;

    {
        size_t wbase = ((((size_t)b * HH + h) * SS + s) * NN + n) * NN + (size_t)qq * 16;
        if constexpr (F32) {
            float* wf = (float*)outv + (size_t)OUT0_ELEMS + wbase;
#pragma unroll
            for (int g = 0; g < 4; ++g) {
                float4 f; f.x = sc[g*4]; f.y = sc[g*4+1]; f.z = sc[g*4+2]; f.w = sc[g*4+3];
                *(float4*)(wf + g * 4) = f;
            }
        } else {
            u16* wo = (u16*)outv + (size_t)OUT0_ELEMS + wbase;
            union { u16 u[16]; uint4 v[2]; } wb;
#pragma unroll
            for (int i = 0; i < 16; ++i) wb.u[i] = f2bf(sc[i]);
            *(uint4*)wo = wb.v[0];
            *(uint4*)(wo + 8) = wb.v[1];
        }
    }

    float ao[32];
#pragma unroll
    for (int d = 0; d < 32; ++d) ao[d] = 0.f;
#pragma unroll
    for (int i = 0; i < 16; ++i) {
        int m = qq * 16 + i;
        float w = sc[i];
#pragma unroll
        for (int j = 0; j < 8; ++j) {
            float4 f = *(const float4*)&sV[m][j * 4];
            ao[j * 4 + 0] += w * f.x; ao[j * 4 + 1] += w * f.y;
            ao[j * 4 + 2] += w * f.z; ao[j * 4 + 3] += w * f.w;
        }
    }
#pragma unroll
    for (int d = 0; d < 32; ++d) {
        ao[d] += __shfl_xor(ao[d], 1);
        ao[d] += __shfl_xor(ao[d], 2);
    }
    {
        size_t abase = ((size_t)bs * NN + n) * DKK + h * DHH + (size_t)qq * 8;
        if constexpr (F32) {
            float* af = (float*)outv + abase;
            float4 f0, f1;
            f0.x = ao[qq*8+0]; f0.y = ao[qq*8+1]; f0.z = ao[qq*8+2]; f0.w = ao[qq*8+3];
            f1.x = ao[qq*8+4]; f1.y = ao[qq*8+5]; f1.z = ao[qq*8+6]; f1.w = ao[qq*8+7];
            *(float4*)af = f0;
            *(float4*)(af + 4) = f1;
        } else {
            union { u16 u[8]; uint4 v; } ob;
#pragma unroll
            for (int u = 0; u < 8; ++u) ob.u[u] = f2bf(ao[qq * 8 + u]);
            *(uint4*)((u16*)outv + abase) = ob.v;
        }
    }
}

template <bool F32>
__global__ __launch_bounds__(256) void k_outproj(
    const void* __restrict__ WOv, const void* __restrict__ bOv,
    void* __restrict__ outv, const int* __restrict__ flag)
{
    if ((flag[0] != 0) != F32) return;

    __shared__ __align__(16) u16 xs[64][264];
    const int t = threadIdx.x;
    const size_t base = (size_t)blockIdx.x * (NN * DKK);

    if constexpr (F32) {
        const float* ag = (const float*)outv + base;
#pragma unroll
        for (int i = 0; i < 16; ++i) {
            int idx = t + (i << 8);
            int r = idx >> 6;
            int c4 = (idx & 63) << 2;
            float4 f = *(const float4*)(ag + (size_t)r * DKK + c4);
            union { u16 u[4]; uint2 v; } pk;
            pk.u[0] = f2bf(f.x); pk.u[1] = f2bf(f.y);
            pk.u[2] = f2bf(f.z); pk.u[3] = f2bf(f.w);
            *(uint2*)&xs[r][c4] = pk.v;
        }
    } else {
        const u16* ag = (const u16*)outv + base;
#pragma unroll
        for (int i = 0; i < 8; ++i) {
            int idx = t + (i << 8);
            int r = idx >> 5;
            int c = (idx & 31) << 3;
            *(uint4*)&xs[r][c] = ((const uint4*)ag)[idx];
        }
    }
    __syncthreads();

    const int n = t >> 2;
    const int jj = t & 3;
    for (int cg = 0; cg < 8; ++cg) {
        const int colbase = cg * 32 + jj * 8;
        float acc[8];
        if constexpr (F32) {
            const float* bb = (const float*)bOv;
#pragma unroll
            for (int u = 0; u < 8; ++u) acc[u] = bb[colbase + u];
        } else {
            const u16* bb = (const u16*)bOv;
#pragma unroll
            for (int u = 0; u < 8; ++u) acc[u] = bf2f(bb[colbase + u]);
        }
        const u16* xr = xs[n];
        if constexpr (F32) {
            const float* W = (const float*)WOv + colbase;
#pragma unroll 4
            for (int kk = 0; kk < DKK; ++kk) {
                float x = bf2f(xr[kk]);
                float4 w0 = *(const float4*)(W + (size_t)kk * DKK);
                float4 w1 = *(const float4*)(W + (size_t)kk * DKK + 4);
                acc[0] += x * w0.x; acc[1] += x * w0.y;
                acc[2] += x * w0.z; acc[3] += x * w0.w;
                acc[4] += x * w1.x; acc[5] += x * w1.y;
                acc[6] += x * w1.z; acc[7] += x * w1.w;
            }
        } else {
            const u16* W = (const u16*)WOv + colbase;
#pragma unroll 4
            for (int kk = 0; kk < DKK; ++kk) {
                float x = bf2f(xr[kk]);
                uint4 wv = *(const uint4*)(W + (size_t)kk * DKK);
                const u16* w8 = (const u16*)&wv;
                acc[0] += x * bf2f(w8[0]); acc[1] += x * bf2f(w8[1]);
                acc[2] += x * bf2f(w8[2]); acc[3] += x * bf2f(w8[3]);
                acc[4] += x * bf2f(w8[4]); acc[5] += x * bf2f(w8[5]);
                acc[6] += x * bf2f(w8[6]); acc[7] += x * bf2f(w8[7]);
            }
        }
        if constexpr (F32) {
            float* og = (float*)outv + base + (size_t)n * DKK + colbase;
            float4 f0, f1;
            f0.x = acc[0]; f0.y = acc[1]; f0.z = acc[2]; f0.w = acc[3];
            f1.x = acc[4]; f1.y = acc[5]; f1.z = acc[6]; f1.w = acc[7];
            *(float4*)og = f0;
            *(float4*)(og + 4) = f1;
        } else {
            union { u16 u[8]; uint4 v; } ob;
#pragma unroll
            for (int u = 0; u < 8; ++u) ob.u[u] = f2bf(acc[u]);
            *(uint4*)((u16*)outv + base + (size_t)n * DKK + colbase) = ob.v;
        }
    }
}

extern "C" void kernel_launch(void* const* d_in, const int* in_sizes, int n_in,
                              void* d_out, int out_size, void* d_ws, size_t ws_size,
                              hipStream_t stream) {
    (void)in_sizes; (void)n_in; (void)out_size;
    int* flag = (int*)d_ws;

    k_detect<<<1, 256, 0, stream>>>((const u16*)d_in[3], flag);

    const size_t WS_NEEDED = 512 + (size_t)8 * 65536 * 2;  // flag + WT hi/lo
    if (ws_size >= WS_NEEDED) {
        k_wt<<<256, 256, 0, stream>>>(d_in[3], d_in[5], d_in[7], d_in[9], d_ws, flag);

        k_attn_mfma<false><<<BB * SS * HH, 256, 0, stream>>>(
            d_in[0], d_in[1], d_in[2], d_in[4], d_in[6], d_in[8],
            d_ws, d_out, flag);
        k_attn_mfma<true><<<BB * SS * HH, 256, 0, stream>>>(
            d_in[0], d_in[1], d_in[2], d_in[4], d_in[6], d_in[8],
            d_ws, d_out, flag);

        k_outproj_mfma<false><<<BB * SS, 256, 0, stream>>>(d_ws, d_in[10], d_out, flag);
        k_outproj_mfma<true><<<BB * SS, 256, 0, stream>>>(d_ws, d_in[10], d_out, flag);
    } else {
        k_attn<false><<<BB * SS * HH, 256, 0, stream>>>(
            d_in[0], d_in[1], d_in[2], d_in[3], d_in[4], d_in[5], d_in[6],
            d_in[7], d_in[8], d_out, flag);
        k_attn<true><<<BB * SS * HH, 256, 0, stream>>>(
            d_in[0], d_in[1], d_in[2], d_in[3], d_in[4], d_in[5], d_in[6],
            d_in[7], d_in[8], d_out, flag);

        k_outproj<false><<<BB * SS, 256, 0, stream>>>(d_in[9], d_in[10], d_out, flag);
        k_outproj<true><<<BB * SS, 256, 0, stream>>>(d_in[9], d_in[10], d_out, flag);
    }
}